// Round 1
// baseline (638.535 us; speedup 1.0000x reference)
//
#include <hip/hip_runtime.h>

// WideComponent: wide = sum of 3 scalar-embedding gathers; cross = 2 gathers
// into a 150M-element weight vector at index f1*D_CAT+f2 (+ block offset).
// Pure gather kernel, B=16384.

#define D_USER 100000
#define D_ITEM 50000
#define D_CAT  1000
#define OFF_IC (D_USER * D_CAT)   // 100,000,000

__global__ __launch_bounds__(256) void wide_cross_kernel(
    const int* __restrict__ user_id,
    const int* __restrict__ item_id,
    const int* __restrict__ category,
    const float* __restrict__ emb_user,
    const float* __restrict__ emb_item,
    const float* __restrict__ emb_cat,
    const float* __restrict__ cross_w,
    float* __restrict__ out,
    int n)
{
    int i = blockIdx.x * blockDim.x + threadIdx.x;
    if (i >= n) return;

    int u  = user_id[i];
    int it = item_id[i];
    int c  = category[i];

    // wide part: match reference add order (u + it + c)
    float wide = emb_user[u] + emb_item[it] + emb_cat[c];

    // cross part: gather of cross_w at the flattened one-hot-outer indices
    long long idx_uc = (long long)u  * D_CAT + c;
    long long idx_ic = (long long)OFF_IC + (long long)it * D_CAT + c;
    float cross = cross_w[idx_uc] + cross_w[idx_ic];

    out[i] = wide + cross;
}

extern "C" void kernel_launch(void* const* d_in, const int* in_sizes, int n_in,
                              void* d_out, int out_size, void* d_ws, size_t ws_size,
                              hipStream_t stream) {
    const int*   user_id  = (const int*)d_in[0];
    const int*   item_id  = (const int*)d_in[1];
    const int*   category = (const int*)d_in[2];
    const float* emb_user = (const float*)d_in[3];
    const float* emb_item = (const float*)d_in[4];
    const float* emb_cat  = (const float*)d_in[5];
    const float* cross_w  = (const float*)d_in[6];
    float* out = (float*)d_out;

    int n = in_sizes[0];  // B = 16384
    int block = 256;
    int grid = (n + block - 1) / block;
    wide_cross_kernel<<<grid, block, 0, stream>>>(
        user_id, item_id, category, emb_user, emb_item, emb_cat, cross_w, out, n);
}

// Round 2
// 637.815 us; speedup vs baseline: 1.0011x; 1.0011x over previous
//
#include <hip/hip_runtime.h>

// WideComponent: wide = sum of 3 scalar-embedding gathers; cross = 2 gathers
// into a 150M-element weight vector at index f1*D_CAT+f2 (+ block offset).
// Pure gather kernel, B=16384 -> 256 waves total.
//
// Launch config: 64-thread blocks (1 wave each), 256 blocks -> one workgroup
// per CU. Spreads the random cross_w gathers across every CU's load queue and
// all XCD L2 channels instead of stacking 4 waves on 64 CUs.

#define D_USER 100000
#define D_ITEM 50000
#define D_CAT  1000
#define OFF_IC (D_USER * D_CAT)   // 100,000,000

__global__ __launch_bounds__(64) void wide_cross_kernel(
    const int* __restrict__ user_id,
    const int* __restrict__ item_id,
    const int* __restrict__ category,
    const float* __restrict__ emb_user,
    const float* __restrict__ emb_item,
    const float* __restrict__ emb_cat,
    const float* __restrict__ cross_w,
    float* __restrict__ out,
    int n)
{
    int i = blockIdx.x * blockDim.x + threadIdx.x;
    if (i >= n) return;

    int u  = user_id[i];
    int it = item_id[i];
    int c  = category[i];

    // Independent gathers — compiler issues all 5 loads before any use.
    float wu = emb_user[u];
    float wi = emb_item[it];
    float wc = emb_cat[c];
    long long idx_uc = (long long)u  * D_CAT + c;
    long long idx_ic = (long long)OFF_IC + (long long)it * D_CAT + c;
    float xu = cross_w[idx_uc];
    float xi = cross_w[idx_ic];

    // Match reference add order: (emb_u + emb_it + emb_c) + (cross_uc + cross_ic)
    out[i] = (wu + wi + wc) + (xu + xi);
}

extern "C" void kernel_launch(void* const* d_in, const int* in_sizes, int n_in,
                              void* d_out, int out_size, void* d_ws, size_t ws_size,
                              hipStream_t stream) {
    const int*   user_id  = (const int*)d_in[0];
    const int*   item_id  = (const int*)d_in[1];
    const int*   category = (const int*)d_in[2];
    const float* emb_user = (const float*)d_in[3];
    const float* emb_item = (const float*)d_in[4];
    const float* emb_cat  = (const float*)d_in[5];
    const float* cross_w  = (const float*)d_in[6];
    float* out = (float*)d_out;

    int n = in_sizes[0];  // B = 16384
    int block = 64;
    int grid = (n + block - 1) / block;  // 256 blocks -> ~1 per CU
    wide_cross_kernel<<<grid, block, 0, stream>>>(
        user_id, item_id, category, emb_user, emb_item, emb_cat, cross_w, out, n);
}